// Round 5
// baseline (893.048 us; speedup 1.0000x reference)
//
#include <hip/hip_runtime.h>

#define N_TOK 262144
#define LATD  128
#define DIMD  256

using f32x4  = __attribute__((ext_vector_type(4)))  float;
using f32x16 = __attribute__((ext_vector_type(16))) float;
using f16x8  = __attribute__((ext_vector_type(8)))  _Float16;

// ---------------- workspace layout (32-bit word offsets) ----------------
#define W_PACK_SYN 0         // 65536 f16 (32768 words): [kt][hi/lo][ct][lane][e]
#define W_PACK_SEM 32768     // 131072 f16 (65536 words)
#define W_CBN_SYN  98304     // 64  f32 ||cb||^2
#define W_CBN_SEM  98368     // 128 f32
#define W_IDX_SYN  98496     // 262144 i32
#define W_IDX_SEM  360640    // 262144 i32
#define W_CNT_SYN  622784    // 64  i32
#define W_CNT_SEM  622848    // 128 i32
#define W_EMB_SYN  622976    // 64x256 f32
#define W_EMB_SEM  639360    // 128x256 f32
#define W_MRK_SYN  672128    // 64x64 i32
#define W_MRK_SEM  676224    // 128x128 i32
#define W_N_SYN    692610    // f32
#define W_N_SEM    692611    // f32
#define W_LOSSP_SYN 692612   // 8192 f32 per-block loss partials
#define W_LOSSP_SEM 700804   // 8192 f32
#define W_ZERO_BEG 622784
#define W_ZERO_END 692612

// ---------------- output layout (float offsets) ----------------
#define OFF_ZQ_SYN  0LL
#define OFF_ZQ_SEM  67108864LL
#define OFF_LOSS    134217728LL
#define OFF_IDX_SYN 134217729LL
#define OFF_IDX_SEM 134479873LL
#define OFF_CB_SYN  134742017LL
#define OFF_CL_SYN  134758401LL
#define OFF_AVG_SYN 134758465LL
#define OFF_ADJ_SYN 134774849LL
#define OFF_CB_SEM  134778945LL
#define OFF_CL_SEM  134811713LL
#define OFF_AVG_SEM 134811841LL
#define OFF_ADJ_SEM 134844609LL

__device__ inline void gload16(const void* g, void* l) {
  __builtin_amdgcn_global_load_lds(
      (const __attribute__((address_space(1))) unsigned int*)g,
      (__attribute__((address_space(3))) unsigned int*)l, 16, 0, 0);
}

__global__ __launch_bounds__(256) void k_init(float* __restrict__ ws) {
  int idx = W_ZERO_BEG + blockIdx.x * 256 + threadIdx.x;
  if (idx < W_ZERO_END) ws[idx] = 0.0f;
}

// Pack Mt = [cb^T | W] into 32x32x16 f16 fragment order, hi + lo halves.
template <int K>
__global__ __launch_bounds__(256) void k_prep_pack(
    const float* __restrict__ cb, const float* __restrict__ W,
    _Float16* __restrict__ pack) {
  constexpr int R   = 2 * K;
  constexpr int NCT = R / 32;
  constexpr int PER_KT = NCT * 512;
  int t = blockIdx.x * 256 + threadIdx.x;   // < 16*PER_KT
  int kt = t / PER_KT;
  int r  = t - kt * PER_KT;
  int ct = r >> 9;
  int l  = (r >> 3) & 63;
  int e  = r & 7;
  int j   = kt * 16 + (l >> 5) * 8 + e;
  int col = ct * 32 + (l & 31);
  float x = (col < K) ? cb[col * DIMD + j] : W[j * K + (col - K)];
  _Float16 h = (_Float16)x;
  _Float16 lo = (_Float16)(x - (float)h);
  pack[(size_t)kt * 2 * PER_KT + r]          = h;
  pack[(size_t)kt * 2 * PER_KT + PER_KT + r] = lo;
}

// ||cb_k||^2.  grid = 192 blocks (64 syn + 128 sem), 256 threads.
__global__ __launch_bounds__(256) void k_prep_norm(
    const float* __restrict__ cbs, const float* __restrict__ cbm,
    float* __restrict__ ws) {
  __shared__ float red[256];
  int k = blockIdx.x;
  const float* src;
  float* dst;
  if (k < 64) { src = cbs + (size_t)k * DIMD; dst = ws + W_CBN_SYN + k; }
  else        { src = cbm + (size_t)(k - 64) * DIMD; dst = ws + W_CBN_SEM + (k - 64); }
  float v = src[threadIdx.x];
  red[threadIdx.x] = v * v;
  __syncthreads();
  for (int s = 128; s > 0; s >>= 1) {
    if (threadIdx.x < s) red[threadIdx.x] += red[threadIdx.x + s];
    __syncthreads();
  }
  if (threadIdx.x == 0) *dst = red[0];
}

// ---- pass A: split-f16 MFMA GEMM + softmax/argmin/zq + loss partials ----
// TB tokens/block; wave owns one 32-row tile x 4 col-tiles (12 MFMA per
// A-conversion).  A staged per-K-chunk [kquad][token] (16B slots), double-
// buffered with B; ONE barrier per K-chunk; S (64 KB) aliases staging.
template <int K>
__global__ __launch_bounds__(256) void k_passA(
    const float* __restrict__ zre, const float* __restrict__ zim,
    const _Float16* __restrict__ pack, const float* __restrict__ cbn,
    const float* __restrict__ cb,  const float* __restrict__ bvec,
    const float* __restrict__ adj, const int* __restrict__ prev,
    float* __restrict__ zq_out, float* __restrict__ idxf_out,
    int* __restrict__ idxi_ws, int* __restrict__ mark_ws,
    float* __restrict__ lossp) {
  constexpr int R   = 2 * K;              // 128 / 256
  constexpr int NCT = R / 32;             // 4 / 8
  constexpr int TB  = (K == 64) ? 128 : 64;
  constexpr int NKT = 16;
  constexpr int PER_KT = NCT * 512;       // f16 per hi (or lo) chunk
  constexpr int BW  = 2 * PER_KT;         // f16 per staged B chunk
  constexpr int TBA = TB * 64;            // A chunk bytes (TB*16k*4B)
  constexpr int BWB = BW * 2;             // B chunk bytes
  constexpr int AITERS = TB * 4 / 256;    // 2 / 1
  constexpr int BITERS = BWB / 4096;      // 2 / 4
  __shared__ __align__(16) float smem[16384];  // staging (dbuf A+B) / S alias
  __shared__ float znl[TB];
  __shared__ float wred2[4];

  const int tid  = threadIdx.x;
  const int lane = tid & 63;
  const int wv   = tid >> 6;
  const int t0   = blockIdx.x * TB;
  const int rt   = (K == 64) ? wv : (wv >> 1);
  const int ct0  = (K == 64) ? 0 : ((wv & 1) * 4);
  char* lds = (char*)smem;

  const int row32 = lane & 31;
  const int kg    = lane >> 5;
  const int tloc  = rt * 32 + row32;

  // ---- staging helpers ----
  auto stageA = [&](int kt, int buf) {
#pragma unroll
    for (int it = 0; it < AITERS; ++it) {
      int s = it * 256 + tid;
      int q = s / TB;
      int t = s % TB;
      int kk = kt * 16 + q * 4;
      const float* g = (kk < 128)
          ? (zre + (size_t)(t0 + t) * LATD + kk)
          : (zim + (size_t)(t0 + t) * LATD + (kk - 128));
      gload16(g, lds + buf * TBA + ((it * 256 + (tid & 192)) << 4));
    }
  };
  auto stageB = [&](int kt, int buf) {
    const _Float16* src = pack + (size_t)kt * BW;
#pragma unroll
    for (int i = 0; i < BITERS; ++i)
      gload16(src + (size_t)(i * 256 + tid) * 8,
              lds + 2 * TBA + buf * BWB + ((i * 256 + (tid & 192)) << 4));
  };

  stageA(0, 0);
  stageB(0, 0);

  f32x16 acc[4];
#pragma unroll
  for (int c = 0; c < 4; ++c)
#pragma unroll
    for (int r = 0; r < 16; ++r) acc[c][r] = 0.0f;
  float zn = 0.0f;

  for (int kt = 0; kt < NKT; ++kt) {
    __syncthreads();                     // stage(kt) complete; bufs(kt+1) free
    if (kt + 1 < NKT) { stageA(kt + 1, (kt + 1) & 1); stageB(kt + 1, (kt + 1) & 1); }
    const float* Ab = (const float*)(lds + (kt & 1) * TBA);
    f32x4 v0 = *(const f32x4*)(Ab + ((2 * kg) * TB + tloc) * 4);
    f32x4 v1 = *(const f32x4*)(Ab + ((2 * kg + 1) * TB + tloc) * 4);
    f16x8 Ah, Al;
#pragma unroll
    for (int e = 0; e < 4; ++e) {
      _Float16 h0 = (_Float16)v0[e];
      Ah[e] = h0;       Al[e] = (_Float16)(v0[e] - (float)h0);
      _Float16 h1 = (_Float16)v1[e];
      Ah[e + 4] = h1;   Al[e + 4] = (_Float16)(v1[e] - (float)h1);
      zn += v0[e] * v0[e];
      zn += v1[e] * v1[e];
    }
    const _Float16* Bp = (const _Float16*)(lds + 2 * TBA + (kt & 1) * BWB);
#pragma unroll
    for (int c = 0; c < 4; ++c) {
      int ct = ct0 + c;
      f16x8 Bh = *(const f16x8*)(Bp + ((size_t)(ct) * 64 + lane) * 8);
      f16x8 Bl = *(const f16x8*)(Bp + ((size_t)(NCT + ct) * 64 + lane) * 8);
      acc[c] = __builtin_amdgcn_mfma_f32_32x32x16_f16(Ah, Bh, acc[c], 0, 0, 0);
      acc[c] = __builtin_amdgcn_mfma_f32_32x32x16_f16(Ah, Bl, acc[c], 0, 0, 0);
      acc[c] = __builtin_amdgcn_mfma_f32_32x32x16_f16(Al, Bh, acc[c], 0, 0, 0);
    }
  }
  // full ||zf_row||^2: combine kg half-sums; one wave per row-tile publishes
  {
    float znt = zn + __shfl_xor(zn, 32);
    if (((K == 64) || (wv & 1) == 0) && lane < 32) znl[rt * 32 + row32] = znt;
  }
  __syncthreads();                       // all reads of staging done; alias as S

  float* S = smem;
#pragma unroll
  for (int c = 0; c < 4; ++c) {
    int col = (ct0 + c) * 32 + row32;
#pragma unroll
    for (int r = 0; r < 16; ++r) {
      int rw = (r & 3) + 8 * (r >> 2) + 4 * kg;
      S[(rt * 32 + rw) * R + col] = acc[c][r];
    }
  }
  __syncthreads();

  // ---- epilogue: one wave per token (stride 4) ----
  const float4* cb4 = (const float4*)cb;
  float4* zq4 = (float4*)zq_out;
  float lacc = 0.0f;
  for (int t = wv; t < TB; t += 4) {
    const int gt = t0 + t;
    const int pv = prev[gt];
    float bv; int bi;
    if (K == 64) {
      float lg = S[t * R + 64 + lane] + bvec[lane];
      float mx = lg;
#pragma unroll
      for (int off = 32; off; off >>= 1) mx = fmaxf(mx, __shfl_xor(mx, off));
      float e = __expf(lg - mx);
      float es = e;
#pragma unroll
      for (int off = 32; off; off >>= 1) es += __shfl_xor(es, off);
      float p  = e / es;
      float av = adj[pv * 64 + lane];
      float sg = 1.0f / (1.0f + __expf(-av));
      bv = cbn[lane] - 2.0f * S[t * R + lane] - 0.8f * sg - 2.0f * p;
      bi = lane;
    } else {
      float lg0 = S[t * R + 128 + lane] + bvec[lane];
      float lg1 = S[t * R + 192 + lane] + bvec[lane + 64];
      float mx = fmaxf(lg0, lg1);
#pragma unroll
      for (int off = 32; off; off >>= 1) mx = fmaxf(mx, __shfl_xor(mx, off));
      float e0 = __expf(lg0 - mx), e1 = __expf(lg1 - mx);
      float es = e0 + e1;
#pragma unroll
      for (int off = 32; off; off >>= 1) es += __shfl_xor(es, off);
      float a0 = adj[pv * 128 + lane], a1 = adj[pv * 128 + 64 + lane];
      float s0 = 1.0f / (1.0f + __expf(-a0));
      float s1 = 1.0f / (1.0f + __expf(-a1));
      float dv0 = cbn[lane]      - 2.0f * S[t * R + lane]      - 0.8f * s0 - 2.0f * (e0 / es);
      float dv1 = cbn[lane + 64] - 2.0f * S[t * R + 64 + lane] - 0.8f * s1 - 2.0f * (e1 / es);
      bv = dv0; bi = lane;
      if (dv1 < dv0) { bv = dv1; bi = lane + 64; }
    }
#pragma unroll
    for (int off = 32; off; off >>= 1) {
      float ov = __shfl_xor(bv, off);
      int   oi = __shfl_xor(bi, off);
      if (ov < bv || (ov == bv && oi < bi)) { bv = ov; bi = oi; }
    }
    if (lane == 0) {
      idxf_out[gt] = (float)bi;
      idxi_ws[gt]  = bi;
      mark_ws[pv * K + bi] = 1;
      lacc += cbn[bi] + znl[t] - 2.0f * S[t * R + bi];
    }
    zq4[(size_t)gt * 64 + lane] = cb4[(size_t)bi * 64 + lane];
  }
  if (lane == 0) wred2[wv] = lacc;
  __syncthreads();
  if (tid == 0)
    lossp[blockIdx.x] = wred2[0] + wred2[1] + wred2[2] + wred2[3];
}

// ---- pass B: embed sums via one-hot MFMA (emb = P^T @ zf), counts via LDS ----
// grid = 256 chunks x 4 col-groups (64 cols each).  TPB=1024 tokens per block.
template <int K>
__global__ __launch_bounds__(256) void k_passB(
    const float* __restrict__ zre, const float* __restrict__ zim,
    const int* __restrict__ idxi,
    float* __restrict__ emb_ws, int* __restrict__ cnt_ws) {
  constexpr int TPB  = 1024;
  constexpr int NCT2 = (K == 64) ? 1 : 2;   // col-tiles per wave
  __shared__ int idxl[TPB];
  __shared__ int cntl[K];
  const int tid  = threadIdx.x;
  const int lane = tid & 63, wv = tid >> 6;
  const int chunk = blockIdx.x >> 2;        // 0..255
  const int cg    = blockIdx.x & 3;         // which 64 of the 256 cols
  const int tbase = chunk * TPB;

  if (tid < K) cntl[tid] = 0;
  __syncthreads();
#pragma unroll
  for (int i = 0; i < TPB / 256; ++i) {
    int id = idxi[tbase + i * 256 + tid];
    idxl[i * 256 + tid] = id;
    if (cg == 0) atomicAdd(&cntl[id], 1);
  }
  __syncthreads();
  if (cg == 0 && tid < K) atomicAdd(&cnt_ws[tid], cntl[tid]);

  const int rt  = (K == 64) ? (wv & 1) : wv;
  const int ct0 = (K == 64) ? (wv >> 1) : 0;
  const int krow = rt * 32 + (lane & 31);
  const int esub = (lane >> 5) * 8;
  const float* zsrc = (cg < 2) ? zre : zim;
  const int cbase = (cg & 1) * 64;          // col base within this z tensor

  f32x16 acc[NCT2];
#pragma unroll
  for (int c = 0; c < NCT2; ++c)
#pragma unroll
    for (int r = 0; r < 16; ++r) acc[c][r] = 0.0f;

  const _Float16 oneh = (_Float16)1.0f, zeroh = (_Float16)0.0f;
  for (int s = 0; s < TPB / 16; ++s) {
    const int tloc = s * 16 + esub;
    f16x8 Af;
#pragma unroll
    for (int e = 0; e < 8; ++e)
      Af[e] = (idxl[tloc + e] == krow) ? oneh : zeroh;
#pragma unroll
    for (int c = 0; c < NCT2; ++c) {
      const float* zp = zsrc + (size_t)(tbase + tloc) * LATD
                        + cbase + (ct0 + c) * 32 + (lane & 31);
      f16x8 Bf;
#pragma unroll
      for (int e = 0; e < 8; ++e)
        Bf[e] = (_Float16)zp[(size_t)e * LATD];
      acc[c] = __builtin_amdgcn_mfma_f32_32x32x16_f16(Af, Bf, acc[c], 0, 0, 0);
    }
  }
#pragma unroll
  for (int c = 0; c < NCT2; ++c)
#pragma unroll
    for (int r = 0; r < 16; ++r) {
      int row = rt * 32 + (r & 3) + 8 * (r >> 2) + 4 * (lane >> 5);
      int col = cg * 64 + (ct0 + c) * 32 + (lane & 31);
      atomicAdd(&emb_ws[row * DIMD + col], acc[c][r]);
    }
}

// ---- finalize 1: cl_new, n sums, loss ----
__global__ __launch_bounds__(256) void k_fin1(
    float* __restrict__ ws, const float* __restrict__ clsi, const float* __restrict__ clmi,
    float* __restrict__ out_cl_syn, float* __restrict__ out_cl_sem, float* __restrict__ out_loss) {
  __shared__ float red[256];
  __shared__ float s1[64], s2[128];
  const int* wsi = (const int*)ws;
  int tid = threadIdx.x;
  float s = 0.0f;
  for (int i = tid; i < 2048; i += 256) s += ws[W_LOSSP_SYN + i];
  for (int i = tid; i < 4096; i += 256) s += ws[W_LOSSP_SEM + i];
  red[tid] = s;
  if (tid < 64) {
    float c  = (float)wsi[W_CNT_SYN + tid];
    float cl = clsi[tid] * 0.99f + 0.01f * c;
    out_cl_syn[tid] = cl; s1[tid] = cl;
  }
  if (tid < 128) {
    float c  = (float)wsi[W_CNT_SEM + tid];
    float cl = clmi[tid] * 0.99f + 0.01f * c;
    out_cl_sem[tid] = cl; s2[tid] = cl;
  }
  __syncthreads();
  for (int st = 128; st > 0; st >>= 1) {
    if (tid < st) red[tid] += red[tid + st];
    __syncthreads();
  }
  if (tid == 0) {
    float n1 = 0.0f; for (int i = 0; i < 64;  ++i) n1 += s1[i];
    float n2 = 0.0f; for (int i = 0; i < 128; ++i) n2 += s2[i];
    ws[W_N_SYN] = n1;
    ws[W_N_SEM] = n2;
    float denom = (float)N_TOK * 256.0f;
    *out_loss = 1.25f * red[0] / denom;
  }
}

// ---- finalize 2: avg_new, cb_new, adj_new ----
__global__ __launch_bounds__(256) void k_fin2(
    const float* __restrict__ ws,
    const float* __restrict__ avgs, const float* __restrict__ avgm,
    const float* __restrict__ adjs, const float* __restrict__ adjm,
    const float* __restrict__ clsi, const float* __restrict__ clmi,
    float* __restrict__ o_cb_syn, float* __restrict__ o_avg_syn, float* __restrict__ o_adj_syn,
    float* __restrict__ o_cb_sem, float* __restrict__ o_avg_sem, float* __restrict__ o_adj_sem) {
  const int* wsi = (const int*)ws;
  int e = blockIdx.x * 256 + threadIdx.x;
  if (e < 16384) {                       // syn avg/cb
    int k = e >> 8;
    float av = avgs[e] * 0.99f + 0.01f * ws[W_EMB_SYN + e];
    o_avg_syn[e] = av;
    float cnt = (float)wsi[W_CNT_SYN + k];
    float cl  = clsi[k] * 0.99f + 0.01f * cnt;
    float n   = ws[W_N_SYN];
    float cs  = (cl + 1e-6f) / (n + (float)(64 * 1e-6)) * n;
    o_cb_syn[e] = av / cs;
  } else if (e < 49152) {                // sem avg/cb
    int e2 = e - 16384;
    int k = e2 >> 8;
    float av = avgm[e2] * 0.99f + 0.01f * ws[W_EMB_SEM + e2];
    o_avg_sem[e2] = av;
    float cnt = (float)wsi[W_CNT_SEM + k];
    float cl  = clmi[k] * 0.99f + 0.01f * cnt;
    float n   = ws[W_N_SEM];
    float cs  = (cl + 1e-6f) / (n + (float)(128 * 1e-6)) * n;
    o_cb_sem[e2] = av / cs;
  } else if (e < 53248) {                // adj syn
    int a = e - 49152;
    float old = adjs[a];
    o_adj_syn[a] = wsi[W_MRK_SYN + a] ? old * 0.995f + 1.0f : old;
  } else if (e < 69632) {                // adj sem
    int a = e - 53248;
    float old = adjm[a];
    o_adj_sem[a] = wsi[W_MRK_SEM + a] ? old * 0.995f + 1.0f : old;
  }
}

extern "C" void kernel_launch(void* const* d_in, const int* in_sizes, int n_in,
                              void* d_out, int out_size, void* d_ws, size_t ws_size,
                              hipStream_t stream) {
  const float* zfre = (const float*)d_in[0];
  const float* zfim = (const float*)d_in[1];
  const float* zsre = (const float*)d_in[2];
  const float* zsim = (const float*)d_in[3];
  const float* cbs  = (const float*)d_in[4];
  const float* cbm  = (const float*)d_in[5];
  const float* Wsy  = (const float*)d_in[6];
  const float* bsy  = (const float*)d_in[7];
  const float* Wse  = (const float*)d_in[8];
  const float* bse  = (const float*)d_in[9];
  const float* clsi = (const float*)d_in[10];
  const float* avgs = (const float*)d_in[11];
  const float* clmi = (const float*)d_in[12];
  const float* avgm = (const float*)d_in[13];
  const float* adjs = (const float*)d_in[14];
  const float* adjm = (const float*)d_in[15];
  const int*   prvs = (const int*)d_in[16];
  const int*   prvm = (const int*)d_in[17];

  float* out = (float*)d_out;
  float* wsf = (float*)d_ws;
  int*   wsi = (int*)d_ws;
  _Float16* wsh = (_Float16*)d_ws;

  k_init<<<(W_ZERO_END - W_ZERO_BEG + 255) / 256, 256, 0, stream>>>(wsf);
  k_prep_pack<64><<<128, 256, 0, stream>>>(cbs, Wsy, wsh + 2 * W_PACK_SYN);
  k_prep_pack<128><<<256, 256, 0, stream>>>(cbm, Wse, wsh + 2 * W_PACK_SEM);
  k_prep_norm<<<192, 256, 0, stream>>>(cbs, cbm, wsf);

  k_passA<64><<<N_TOK / 128, 256, 0, stream>>>(
      zfre, zfim, wsh + 2 * W_PACK_SYN, wsf + W_CBN_SYN, cbs, bsy, adjs, prvs,
      out + OFF_ZQ_SYN, out + OFF_IDX_SYN, wsi + W_IDX_SYN, wsi + W_MRK_SYN,
      wsf + W_LOSSP_SYN);
  k_passA<128><<<N_TOK / 64, 256, 0, stream>>>(
      zsre, zsim, wsh + 2 * W_PACK_SEM, wsf + W_CBN_SEM, cbm, bse, adjm, prvm,
      out + OFF_ZQ_SEM, out + OFF_IDX_SEM, wsi + W_IDX_SEM, wsi + W_MRK_SEM,
      wsf + W_LOSSP_SEM);

  k_passB<64><<<1024, 256, 0, stream>>>(
      zfre, zfim, wsi + W_IDX_SYN, wsf + W_EMB_SYN, wsi + W_CNT_SYN);
  k_passB<128><<<1024, 256, 0, stream>>>(
      zsre, zsim, wsi + W_IDX_SEM, wsf + W_EMB_SEM, wsi + W_CNT_SEM);

  k_fin1<<<1, 256, 0, stream>>>(wsf, clsi, clmi,
      out + OFF_CL_SYN, out + OFF_CL_SEM, out + OFF_LOSS);
  k_fin2<<<272, 256, 0, stream>>>(wsf, avgs, avgm, adjs, adjm, clsi, clmi,
      out + OFF_CB_SYN, out + OFF_AVG_SYN, out + OFF_ADJ_SYN,
      out + OFF_CB_SEM, out + OFF_AVG_SEM, out + OFF_ADJ_SEM);
}

// Round 6
// 800.579 us; speedup vs baseline: 1.1155x; 1.1155x over previous
//
#include <hip/hip_runtime.h>

#define N_TOK 262144
#define LATD  128
#define DIMD  256

using f32x4  = __attribute__((ext_vector_type(4)))  float;
using f32x16 = __attribute__((ext_vector_type(16))) float;
using f16x8  = __attribute__((ext_vector_type(8)))  _Float16;

// ---------------- workspace layout (32-bit word offsets) ----------------
#define W_PACK_SYN 0         // 65536 f16 (32768 words): [kt][hi/lo][ct][lane][e]
#define W_PACK_SEM 32768     // 131072 f16 (65536 words)
#define W_CBN_SYN  98304     // 64  f32 ||cb||^2
#define W_CBN_SEM  98368     // 128 f32
#define W_IDX_SYN  98496     // 262144 i32
#define W_IDX_SEM  360640    // 262144 i32
#define W_CNT_SYN  622784    // 64  i32
#define W_CNT_SEM  622848    // 128 i32
#define W_EMB_SYN  622976    // 64x256 f32
#define W_EMB_SEM  639360    // 128x256 f32
#define W_MRK_SYN  672128    // 64x64 i32
#define W_MRK_SEM  676224    // 128x128 i32
#define W_LOSSP_SYN 692612   // 4096 f32 per-block loss partials
#define W_LOSSP_SEM 700804   // 4096 f32
#define W_ZERO_BEG 622784
#define W_ZERO_END 692612

// ---------------- output layout (float offsets) ----------------
#define OFF_ZQ_SYN  0LL
#define OFF_ZQ_SEM  67108864LL
#define OFF_LOSS    134217728LL
#define OFF_IDX_SYN 134217729LL
#define OFF_IDX_SEM 134479873LL
#define OFF_CB_SYN  134742017LL
#define OFF_CL_SYN  134758401LL
#define OFF_AVG_SYN 134758465LL
#define OFF_ADJ_SYN 134774849LL
#define OFF_CB_SEM  134778945LL
#define OFF_CL_SEM  134811713LL
#define OFF_AVG_SEM 134811841LL
#define OFF_ADJ_SEM 134844609LL

__global__ __launch_bounds__(256) void k_init(float* __restrict__ ws) {
  int idx = W_ZERO_BEG + blockIdx.x * 256 + threadIdx.x;
  if (idx < W_ZERO_END) ws[idx] = 0.0f;
}

// Pack Mt = [cb^T | W] into 32x32x16 f16 fragment order, hi + lo halves.
// Used as the MFMA *A* operand now (frag layout is identical to B's).
template <int K>
__global__ __launch_bounds__(256) void k_prep_pack(
    const float* __restrict__ cb, const float* __restrict__ W,
    _Float16* __restrict__ pack) {
  constexpr int R   = 2 * K;
  constexpr int NCT = R / 32;
  constexpr int PER_KT = NCT * 512;
  int t = blockIdx.x * 256 + threadIdx.x;   // < 16*PER_KT
  int kt = t / PER_KT;
  int r  = t - kt * PER_KT;
  int ct = r >> 9;
  int l  = (r >> 3) & 63;
  int e  = r & 7;
  int j   = kt * 16 + (l >> 5) * 8 + e;
  int col = ct * 32 + (l & 31);
  float x = (col < K) ? cb[col * DIMD + j] : W[j * K + (col - K)];
  _Float16 h = (_Float16)x;
  _Float16 lo = (_Float16)(x - (float)h);
  pack[(size_t)kt * 2 * PER_KT + r]          = h;
  pack[(size_t)kt * 2 * PER_KT + PER_KT + r] = lo;
}

// ||cb_k||^2.  grid = 192 blocks (64 syn + 128 sem), 256 threads.
__global__ __launch_bounds__(256) void k_prep_norm(
    const float* __restrict__ cbs, const float* __restrict__ cbm,
    float* __restrict__ ws) {
  __shared__ float red[256];
  int k = blockIdx.x;
  const float* src;
  float* dst;
  if (k < 64) { src = cbs + (size_t)k * DIMD; dst = ws + W_CBN_SYN + k; }
  else        { src = cbm + (size_t)(k - 64) * DIMD; dst = ws + W_CBN_SEM + (k - 64); }
  float v = src[threadIdx.x];
  red[threadIdx.x] = v * v;
  __syncthreads();
  for (int s = 128; s > 0; s >>= 1) {
    if (threadIdx.x < s) red[threadIdx.x] += red[threadIdx.x + s];
    __syncthreads();
  }
  if (threadIdx.x == 0) *dst = red[0];
}

// ---- pass A: LDS-free swapped-operand split-f16 MFMA ----
// D[entry][token]: A = pack (entries x k, from L2), B = z (k x tokens).
// Block = 4 waves / 64 tokens.  wave role (wv&1): 0 = dist entries,
// 1 = logit entries; token group = wv>>1.  Token's entries are lane-local
// (lane j & j+32) -> softmax/argmin/loss in registers; p handed via LDS.
template <int K>
__global__ __launch_bounds__(256) void k_passA(
    const float* __restrict__ zre, const float* __restrict__ zim,
    const _Float16* __restrict__ pack, const float* __restrict__ cbn,
    const float* __restrict__ cb,  const float* __restrict__ bvec,
    const float* __restrict__ adj, const int* __restrict__ prev,
    float* __restrict__ zq_out, float* __restrict__ idxf_out,
    int* __restrict__ idxi_ws, int* __restrict__ mark_ws,
    float* __restrict__ lossp) {
  constexpr int NCT = (2 * K) / 32;     // 4 / 8 entry tiles total
  constexpr int NT  = NCT / 2;          // 2 / 4 tiles per wave
  constexpr int PER_KT = NCT * 512;     // f16 per hi (or lo) k-chunk
  __shared__ float p_lds[64 * K];
  __shared__ int   bi_lds[64];
  __shared__ float wred2[2];

  const int tid  = threadIdx.x;
  const int lane = tid & 63;
  const int wv   = tid >> 6;
  const int kg   = lane >> 5;
  const int j    = lane & 31;
  const int role = wv & 1;
  const int tg   = wv >> 1;
  const int t0   = blockIdx.x * 64;
  const int gt   = t0 + tg * 32 + j;    // this lane's token

  f32x16 acc[NT];
#pragma unroll
  for (int t = 0; t < NT; ++t)
#pragma unroll
    for (int r = 0; r < 16; ++r) acc[t][r] = 0.0f;
  float zn = 0.0f;

  const int ctbase = role * NT;
#pragma unroll 2
  for (int kt = 0; kt < 16; ++kt) {
    const float* zsrc = (kt < 8) ? zre : zim;
    const float* zp = zsrc + (size_t)gt * LATD + (kt & 7) * 16 + kg * 8;
    f32x4 v0 = *(const f32x4*)zp;
    f32x4 v1 = *(const f32x4*)(zp + 4);
    f16x8 Bh, Bl;
#pragma unroll
    for (int e = 0; e < 4; ++e) {
      _Float16 h0 = (_Float16)v0[e];
      Bh[e] = h0;       Bl[e] = (_Float16)(v0[e] - (float)h0);
      _Float16 h1 = (_Float16)v1[e];
      Bh[e + 4] = h1;   Bl[e + 4] = (_Float16)(v1[e] - (float)h1);
      zn += v0[e] * v0[e];
      zn += v1[e] * v1[e];
    }
    const _Float16* pk = pack + (size_t)kt * 2 * PER_KT + lane * 8;
#pragma unroll
    for (int t = 0; t < NT; ++t) {
      f16x8 Ah = *(const f16x8*)(pk + (size_t)(ctbase + t) * 512);
      f16x8 Al = *(const f16x8*)(pk + PER_KT + (size_t)(ctbase + t) * 512);
      acc[t] = __builtin_amdgcn_mfma_f32_32x32x16_f16(Ah, Bh, acc[t], 0, 0, 0);
      acc[t] = __builtin_amdgcn_mfma_f32_32x32x16_f16(Ah, Bl, acc[t], 0, 0, 0);
      acc[t] = __builtin_amdgcn_mfma_f32_32x32x16_f16(Al, Bh, acc[t], 0, 0, 0);
    }
  }

  int pv = 0;
  if (role == 1) {
    // ---- softmax over this token's K logits (in-register) ----
    float mx = -1e30f;
#pragma unroll
    for (int t = 0; t < NT; ++t)
#pragma unroll
      for (int r = 0; r < 16; ++r) {
        int e = t * 32 + (r & 3) + 8 * (r >> 2) + 4 * kg;
        acc[t][r] += bvec[e];
        mx = fmaxf(mx, acc[t][r]);
      }
    mx = fmaxf(mx, __shfl_xor(mx, 32));
    float es = 0.0f;
#pragma unroll
    for (int t = 0; t < NT; ++t)
#pragma unroll
      for (int r = 0; r < 16; ++r) {
        acc[t][r] = __expf(acc[t][r] - mx);
        es += acc[t][r];
      }
    es += __shfl_xor(es, 32);
    float inv = 1.0f / es;
    float* prow = &p_lds[(tg * 32 + j) * K];
#pragma unroll
    for (int t = 0; t < NT; ++t)
#pragma unroll
      for (int r = 0; r < 16; ++r) {
        int e = t * 32 + (r & 3) + 8 * (r >> 2) + 4 * kg;
        prow[e] = acc[t][r] * inv;
      }
  } else {
    pv = prev[gt];
  }
  __syncthreads();

  if (role == 0) {
    // ---- biased argmin over this token's K dist entries ----
    const float* adjrow = adj + (size_t)pv * K;
    const float* prow   = &p_lds[(tg * 32 + j) * K];
    float best = -1e30f; int bidx = 0; float bdot = 0.0f;
#pragma unroll
    for (int t = 0; t < NT; ++t)
#pragma unroll
      for (int r = 0; r < 16; ++r) {
        int e = t * 32 + (r & 3) + 8 * (r >> 2) + 4 * kg;
        float dot = acc[t][r];
        float av  = adjrow[e];
        float sg  = 1.0f / (1.0f + __expf(-av));
        float sc  = dot - 0.5f * cbn[e] + 0.4f * sg + prow[e];
        if (sc > best || (sc == best && e < bidx)) {
          best = sc; bidx = e; bdot = dot;
        }
      }
    {
      float ob = __shfl_xor(best, 32);
      int   oi = __shfl_xor(bidx, 32);
      float od = __shfl_xor(bdot, 32);
      if (ob > best || (ob == best && oi < bidx)) { best = ob; bidx = oi; bdot = od; }
    }
    float znf = zn + __shfl_xor(zn, 32);
    float lj = 0.0f;
    if (lane < 32) {
      idxf_out[gt] = (float)bidx;
      idxi_ws[gt]  = bidx;
      mark_ws[pv * K + bidx] = 1;
      bi_lds[tg * 32 + j] = bidx;
      lj = cbn[bidx] + znf - 2.0f * bdot;
    }
#pragma unroll
    for (int off = 32; off; off >>= 1) lj += __shfl_xor(lj, off);
    if (lane == 0) wred2[tg] = lj;
  }
  __syncthreads();

  // ---- zq gather-write: each wave writes 16 token rows (1 KB each) ----
  const float4* cb4 = (const float4*)cb;
  float4* zq4 = (float4*)zq_out;
#pragma unroll
  for (int i = 0; i < 16; ++i) {
    int tok = wv * 16 + i;
    int bi  = bi_lds[tok];
    zq4[(size_t)(t0 + tok) * 64 + lane] = cb4[(size_t)bi * 64 + lane];
  }
  if (tid == 0) lossp[blockIdx.x] = wred2[0] + wred2[1];
}

// ---- pass B: embed sums via one-hot MFMA (emb = P^T @ zf), counts via LDS ----
// grid = 256 chunks x 4 col-groups (64 cols each).  TPB=1024 tokens per block.
template <int K>
__global__ __launch_bounds__(256) void k_passB(
    const float* __restrict__ zre, const float* __restrict__ zim,
    const int* __restrict__ idxi,
    float* __restrict__ emb_ws, int* __restrict__ cnt_ws) {
  constexpr int TPB  = 1024;
  constexpr int NCT2 = (K == 64) ? 1 : 2;   // col-tiles per wave
  __shared__ int idxl[TPB];
  __shared__ int cntl[K];
  const int tid  = threadIdx.x;
  const int lane = tid & 63, wv = tid >> 6;
  const int chunk = blockIdx.x >> 2;        // 0..255
  const int cg    = blockIdx.x & 3;         // which 64 of the 256 cols
  const int tbase = chunk * TPB;

  if (tid < K) cntl[tid] = 0;
  __syncthreads();
#pragma unroll
  for (int i = 0; i < TPB / 256; ++i) {
    int id = idxi[tbase + i * 256 + tid];
    idxl[i * 256 + tid] = id;
    if (cg == 0) atomicAdd(&cntl[id], 1);
  }
  __syncthreads();
  if (cg == 0 && tid < K) atomicAdd(&cnt_ws[tid], cntl[tid]);

  const int rt  = (K == 64) ? (wv & 1) : wv;
  const int ct0 = (K == 64) ? (wv >> 1) : 0;
  const int krow = rt * 32 + (lane & 31);
  const int esub = (lane >> 5) * 8;
  const float* zsrc = (cg < 2) ? zre : zim;
  const int cbase = (cg & 1) * 64;          // col base within this z tensor

  f32x16 acc[NCT2];
#pragma unroll
  for (int c = 0; c < NCT2; ++c)
#pragma unroll
    for (int r = 0; r < 16; ++r) acc[c][r] = 0.0f;

  const _Float16 oneh = (_Float16)1.0f, zeroh = (_Float16)0.0f;
  for (int s = 0; s < TPB / 16; ++s) {
    const int tloc = s * 16 + esub;
    f16x8 Af;
#pragma unroll
    for (int e = 0; e < 8; ++e)
      Af[e] = (idxl[tloc + e] == krow) ? oneh : zeroh;
#pragma unroll
    for (int c = 0; c < NCT2; ++c) {
      const float* zp = zsrc + (size_t)(tbase + tloc) * LATD
                        + cbase + (ct0 + c) * 32 + (lane & 31);
      f16x8 Bf;
#pragma unroll
      for (int e = 0; e < 8; ++e)
        Bf[e] = (_Float16)zp[(size_t)e * LATD];
      acc[c] = __builtin_amdgcn_mfma_f32_32x32x16_f16(Af, Bf, acc[c], 0, 0, 0);
    }
  }
#pragma unroll
  for (int c = 0; c < NCT2; ++c)
#pragma unroll
    for (int r = 0; r < 16; ++r) {
      int row = rt * 32 + (r & 3) + 8 * (r >> 2) + 4 * (lane >> 5);
      int col = cg * 64 + (ct0 + c) * 32 + (lane & 31);
      atomicAdd(&emb_ws[row * DIMD + col], acc[c][r]);
    }
}

// ---- finalize 1: cl_new, n sums, loss ----
__global__ __launch_bounds__(256) void k_fin1(
    float* __restrict__ ws, const float* __restrict__ clsi, const float* __restrict__ clmi,
    float* __restrict__ out_cl_syn, float* __restrict__ out_cl_sem, float* __restrict__ out_loss) {
  __shared__ float red[256];
  __shared__ float s1[64], s2[128];
  const int* wsi = (const int*)ws;
  int tid = threadIdx.x;
  float s = 0.0f;
  for (int i = tid; i < 4096; i += 256) s += ws[W_LOSSP_SYN + i];
  for (int i = tid; i < 4096; i += 256) s += ws[W_LOSSP_SEM + i];
  red[tid] = s;
  if (tid < 64) {
    float c  = (float)wsi[W_CNT_SYN + tid];
    float cl = clsi[tid] * 0.99f + 0.01f * c;
    out_cl_syn[tid] = cl; s1[tid] = cl;
  }
  if (tid < 128) {
    float c  = (float)wsi[W_CNT_SEM + tid];
    float cl = clmi[tid] * 0.99f + 0.01f * c;
    out_cl_sem[tid] = cl; s2[tid] = cl;
  }
  __syncthreads();
  for (int st = 128; st > 0; st >>= 1) {
    if (tid < st) red[tid] += red[tid + st];
    __syncthreads();
  }
  if (tid == 0) {
    float n1 = 0.0f; for (int i = 0; i < 64;  ++i) n1 += s1[i];
    float n2 = 0.0f; for (int i = 0; i < 128; ++i) n2 += s2[i];
    ws[W_LOSSP_SYN + 4096] = n1;   // stash n_syn
    ws[W_LOSSP_SEM + 4096] = n2;   // stash n_sem
    float denom = (float)N_TOK * 256.0f;
    *out_loss = 1.25f * red[0] / denom;
  }
}

// ---- finalize 2: avg_new, cb_new, adj_new ----
__global__ __launch_bounds__(256) void k_fin2(
    const float* __restrict__ ws,
    const float* __restrict__ avgs, const float* __restrict__ avgm,
    const float* __restrict__ adjs, const float* __restrict__ adjm,
    const float* __restrict__ clsi, const float* __restrict__ clmi,
    float* __restrict__ o_cb_syn, float* __restrict__ o_avg_syn, float* __restrict__ o_adj_syn,
    float* __restrict__ o_cb_sem, float* __restrict__ o_avg_sem, float* __restrict__ o_adj_sem) {
  const int* wsi = (const int*)ws;
  int e = blockIdx.x * 256 + threadIdx.x;
  if (e < 16384) {                       // syn avg/cb
    int k = e >> 8;
    float av = avgs[e] * 0.99f + 0.01f * ws[W_EMB_SYN + e];
    o_avg_syn[e] = av;
    float cnt = (float)wsi[W_CNT_SYN + k];
    float cl  = clsi[k] * 0.99f + 0.01f * cnt;
    float n   = ws[W_LOSSP_SYN + 4096];
    float cs  = (cl + 1e-6f) / (n + (float)(64 * 1e-6)) * n;
    o_cb_syn[e] = av / cs;
  } else if (e < 49152) {                // sem avg/cb
    int e2 = e - 16384;
    int k = e2 >> 8;
    float av = avgm[e2] * 0.99f + 0.01f * ws[W_EMB_SEM + e2];
    o_avg_sem[e2] = av;
    float cnt = (float)wsi[W_CNT_SEM + k];
    float cl  = clmi[k] * 0.99f + 0.01f * cnt;
    float n   = ws[W_LOSSP_SEM + 4096];
    float cs  = (cl + 1e-6f) / (n + (float)(128 * 1e-6)) * n;
    o_cb_sem[e2] = av / cs;
  } else if (e < 53248) {                // adj syn
    int a = e - 49152;
    float old = adjs[a];
    o_adj_syn[a] = wsi[W_MRK_SYN + a] ? old * 0.995f + 1.0f : old;
  } else if (e < 69632) {                // adj sem
    int a = e - 53248;
    float old = adjm[a];
    o_adj_sem[a] = wsi[W_MRK_SEM + a] ? old * 0.995f + 1.0f : old;
  }
}

extern "C" void kernel_launch(void* const* d_in, const int* in_sizes, int n_in,
                              void* d_out, int out_size, void* d_ws, size_t ws_size,
                              hipStream_t stream) {
  const float* zfre = (const float*)d_in[0];
  const float* zfim = (const float*)d_in[1];
  const float* zsre = (const float*)d_in[2];
  const float* zsim = (const float*)d_in[3];
  const float* cbs  = (const float*)d_in[4];
  const float* cbm  = (const float*)d_in[5];
  const float* Wsy  = (const float*)d_in[6];
  const float* bsy  = (const float*)d_in[7];
  const float* Wse  = (const float*)d_in[8];
  const float* bse  = (const float*)d_in[9];
  const float* clsi = (const float*)d_in[10];
  const float* avgs = (const float*)d_in[11];
  const float* clmi = (const float*)d_in[12];
  const float* avgm = (const float*)d_in[13];
  const float* adjs = (const float*)d_in[14];
  const float* adjm = (const float*)d_in[15];
  const int*   prvs = (const int*)d_in[16];
  const int*   prvm = (const int*)d_in[17];

  float* out = (float*)d_out;
  float* wsf = (float*)d_ws;
  int*   wsi = (int*)d_ws;
  _Float16* wsh = (_Float16*)d_ws;

  k_init<<<(W_ZERO_END - W_ZERO_BEG + 255) / 256, 256, 0, stream>>>(wsf);
  k_prep_pack<64><<<128, 256, 0, stream>>>(cbs, Wsy, wsh + 2 * W_PACK_SYN);
  k_prep_pack<128><<<256, 256, 0, stream>>>(cbm, Wse, wsh + 2 * W_PACK_SEM);
  k_prep_norm<<<192, 256, 0, stream>>>(cbs, cbm, wsf);

  k_passA<64><<<N_TOK / 64, 256, 0, stream>>>(
      zfre, zfim, wsh + 2 * W_PACK_SYN, wsf + W_CBN_SYN, cbs, bsy, adjs, prvs,
      out + OFF_ZQ_SYN, out + OFF_IDX_SYN, wsi + W_IDX_SYN, wsi + W_MRK_SYN,
      wsf + W_LOSSP_SYN);
  k_passA<128><<<N_TOK / 64, 256, 0, stream>>>(
      zsre, zsim, wsh + 2 * W_PACK_SEM, wsf + W_CBN_SEM, cbm, bse, adjm, prvm,
      out + OFF_ZQ_SEM, out + OFF_IDX_SEM, wsi + W_IDX_SEM, wsi + W_MRK_SEM,
      wsf + W_LOSSP_SEM);

  k_passB<64><<<1024, 256, 0, stream>>>(
      zfre, zfim, wsi + W_IDX_SYN, wsf + W_EMB_SYN, wsi + W_CNT_SYN);
  k_passB<128><<<1024, 256, 0, stream>>>(
      zsre, zsim, wsi + W_IDX_SEM, wsf + W_EMB_SEM, wsi + W_CNT_SEM);

  k_fin1<<<1, 256, 0, stream>>>(wsf, clsi, clmi,
      out + OFF_CL_SYN, out + OFF_CL_SEM, out + OFF_LOSS);
  k_fin2<<<272, 256, 0, stream>>>(wsf, avgs, avgm, adjs, adjm, clsi, clmi,
      out + OFF_CB_SYN, out + OFF_AVG_SYN, out + OFF_ADJ_SYN,
      out + OFF_CB_SEM, out + OFF_AVG_SEM, out + OFF_ADJ_SEM);
}

// Round 7
// 663.510 us; speedup vs baseline: 1.3459x; 1.2066x over previous
//
#include <hip/hip_runtime.h>

#define N_TOK 262144
#define LATD  128
#define DIMD  256

using f32x4  = __attribute__((ext_vector_type(4)))  float;
using f32x16 = __attribute__((ext_vector_type(16))) float;
using f16x8  = __attribute__((ext_vector_type(8)))  _Float16;

// ---------------- workspace layout (32-bit word offsets) ----------------
#define W_PACK_SYN 0         // 65536 f16 (32768 words): [kt][hi/lo][ct][lane][e]
#define W_PACK_SEM 32768     // 131072 f16 (65536 words)
#define W_CBN_SYN  98304     // 64  f32 ||cb||^2
#define W_CBN_SEM  98368     // 128 f32
#define W_IDX_SYN  98496     // 262144 i32
#define W_IDX_SEM  360640    // 262144 i32
#define W_CNT_SYN  622784    // 64  i32
#define W_CNT_SEM  622848    // 128 i32
#define W_EMB_SYN  622976    // 64x256 f32
#define W_EMB_SEM  639360    // 128x256 f32
#define W_MRK_SYN  672128    // 64x64 i32
#define W_MRK_SEM  676224    // 128x128 i32
#define W_LOSSP_SYN 692612   // 2048 f32 per-block loss partials (+n stash at +4096)
#define W_LOSSP_SEM 700804   // 2048 f32 (+n stash at +4096)
#define W_ZERO_BEG 622784
#define W_ZERO_END 692612

// ---------------- output layout (float offsets) ----------------
#define OFF_ZQ_SYN  0LL
#define OFF_ZQ_SEM  67108864LL
#define OFF_LOSS    134217728LL
#define OFF_IDX_SYN 134217729LL
#define OFF_IDX_SEM 134479873LL
#define OFF_CB_SYN  134742017LL
#define OFF_CL_SYN  134758401LL
#define OFF_AVG_SYN 134758465LL
#define OFF_ADJ_SYN 134774849LL
#define OFF_CB_SEM  134778945LL
#define OFF_CL_SEM  134811713LL
#define OFF_AVG_SEM 134811841LL
#define OFF_ADJ_SEM 134844609LL

__global__ __launch_bounds__(256) void k_init(float* __restrict__ ws) {
  int idx = W_ZERO_BEG + blockIdx.x * 256 + threadIdx.x;
  if (idx < W_ZERO_END) ws[idx] = 0.0f;
}

// Pack Mt = [cb^T | W] into 32x32x16 f16 fragment order, hi + lo halves.
// Used as the MFMA *A* operand (entry rows x k).
template <int K>
__global__ __launch_bounds__(256) void k_prep_pack(
    const float* __restrict__ cb, const float* __restrict__ W,
    _Float16* __restrict__ pack) {
  constexpr int R   = 2 * K;
  constexpr int NCT = R / 32;
  constexpr int PER_KT = NCT * 512;
  int t = blockIdx.x * 256 + threadIdx.x;   // < 16*PER_KT
  int kt = t / PER_KT;
  int r  = t - kt * PER_KT;
  int ct = r >> 9;
  int l  = (r >> 3) & 63;
  int e  = r & 7;
  int j   = kt * 16 + (l >> 5) * 8 + e;
  int col = ct * 32 + (l & 31);
  float x = (col < K) ? cb[col * DIMD + j] : W[j * K + (col - K)];
  _Float16 h = (_Float16)x;
  _Float16 lo = (_Float16)(x - (float)h);
  pack[(size_t)kt * 2 * PER_KT + r]          = h;
  pack[(size_t)kt * 2 * PER_KT + PER_KT + r] = lo;
}

// ||cb_k||^2.  grid = 192 blocks (64 syn + 128 sem), 256 threads.
__global__ __launch_bounds__(256) void k_prep_norm(
    const float* __restrict__ cbs, const float* __restrict__ cbm,
    float* __restrict__ ws) {
  __shared__ float red[256];
  int k = blockIdx.x;
  const float* src;
  float* dst;
  if (k < 64) { src = cbs + (size_t)k * DIMD; dst = ws + W_CBN_SYN + k; }
  else        { src = cbm + (size_t)(k - 64) * DIMD; dst = ws + W_CBN_SEM + (k - 64); }
  float v = src[threadIdx.x];
  red[threadIdx.x] = v * v;
  __syncthreads();
  for (int s = 128; s > 0; s >>= 1) {
    if (threadIdx.x < s) red[threadIdx.x] += red[threadIdx.x + s];
    __syncthreads();
  }
  if (threadIdx.x == 0) *dst = red[0];
}

// ---- pass A: merged-role, LDS-free swapped-operand split-f16 MFMA ----
// Each wave owns 32 tokens and computes ALL 2K entry rows (dist + logit
// tiles).  D[entry][token]: token = lane&31, entry rows register-local.
// Softmax p[e] and dist dot[e] share (tile,reg) index -> epilogue is pure
// register math + one shfl_xor(32) pair combine.  No staging, no barriers
// in the K-loop, 16 B LDS total.
template <int K>
__global__ __launch_bounds__(256, 2) void k_passA(
    const float* __restrict__ zre, const float* __restrict__ zim,
    const _Float16* __restrict__ pack, const float* __restrict__ cbn,
    const float* __restrict__ cb,  const float* __restrict__ bvec,
    const float* __restrict__ adj, const int* __restrict__ prev,
    float* __restrict__ zq_out, float* __restrict__ idxf_out,
    int* __restrict__ idxi_ws, int* __restrict__ mark_ws,
    float* __restrict__ lossp) {
  constexpr int NCT = K / 16;           // total 32-row tiles (2K/32): 4 / 8
  constexpr int NH  = K / 32;           // tiles per role: 2 / 4
  constexpr int PER_KT = NCT * 512;     // f16 per hi (or lo) k-chunk
  __shared__ float wred[4];

  const int tid  = threadIdx.x;
  const int lane = tid & 63;
  const int wv   = tid >> 6;
  const int kg   = lane >> 5;
  const int j    = lane & 31;
  const int t0   = blockIdx.x * 128 + wv * 32;
  const int gt   = t0 + j;              // this lane's token

  f32x16 acc[NCT];
#pragma unroll
  for (int t = 0; t < NCT; ++t)
#pragma unroll
    for (int r = 0; r < 16; ++r) acc[t][r] = 0.0f;
  float zn = 0.0f;

#pragma unroll 2
  for (int kt = 0; kt < 16; ++kt) {
    const float* zsrc = (kt < 8) ? zre : zim;
    const float* zp = zsrc + (size_t)gt * LATD + (kt & 7) * 16 + kg * 8;
    f32x4 v0 = *(const f32x4*)zp;
    f32x4 v1 = *(const f32x4*)(zp + 4);
    f16x8 Bh, Bl;
#pragma unroll
    for (int e = 0; e < 4; ++e) {
      _Float16 h0 = (_Float16)v0[e];
      Bh[e] = h0;       Bl[e] = (_Float16)(v0[e] - (float)h0);
      _Float16 h1 = (_Float16)v1[e];
      Bh[e + 4] = h1;   Bl[e + 4] = (_Float16)(v1[e] - (float)h1);
      zn += v0[e] * v0[e];
      zn += v1[e] * v1[e];
    }
    const _Float16* pk = pack + (size_t)kt * 2 * PER_KT + lane * 8;
#pragma unroll
    for (int t = 0; t < NCT; ++t) {
      f16x8 Ah = *(const f16x8*)(pk + (size_t)t * 512);
      f16x8 Al = *(const f16x8*)(pk + PER_KT + (size_t)t * 512);
      acc[t] = __builtin_amdgcn_mfma_f32_32x32x16_f16(Ah, Bh, acc[t], 0, 0, 0);
      acc[t] = __builtin_amdgcn_mfma_f32_32x32x16_f16(Ah, Bl, acc[t], 0, 0, 0);
      acc[t] = __builtin_amdgcn_mfma_f32_32x32x16_f16(Al, Bh, acc[t], 0, 0, 0);
    }
  }

  const int pv = prev[gt];

  // ---- softmax over logit tiles (NH..NCT-1), in-register ----
  float mx = -1e30f;
#pragma unroll
  for (int t = 0; t < NH; ++t)
#pragma unroll
    for (int q = 0; q < 4; ++q) {
      f32x4 bv4 = *(const f32x4*)&bvec[t * 32 + 8 * q + 4 * kg];
#pragma unroll
      for (int b = 0; b < 4; ++b) {
        acc[NH + t][4 * q + b] += bv4[b];
        mx = fmaxf(mx, acc[NH + t][4 * q + b]);
      }
    }
  mx = fmaxf(mx, __shfl_xor(mx, 32));
  float es = 0.0f;
#pragma unroll
  for (int t = 0; t < NH; ++t)
#pragma unroll
    for (int r = 0; r < 16; ++r) {
      acc[NH + t][r] = __expf(acc[NH + t][r] - mx);
      es += acc[NH + t][r];
    }
  es += __shfl_xor(es, 32);
  const float inv = 1.0f / es;

  // ---- biased argmin (as argmax of sc = dot - cbn/2 + 0.4 sg + p) ----
  const float* adjrow = adj + (size_t)pv * K;
  float best = -1e30f; int bidx = 0; float bdot = 0.0f;
#pragma unroll
  for (int t = 0; t < NH; ++t)
#pragma unroll
    for (int q = 0; q < 4; ++q) {
      const int e0 = t * 32 + 8 * q + 4 * kg;
      f32x4 cb4v = *(const f32x4*)&cbn[e0];
      f32x4 ad4  = *(const f32x4*)&adjrow[e0];
#pragma unroll
      for (int b = 0; b < 4; ++b) {
        int r = 4 * q + b;
        float dot = acc[t][r];
        float sg  = 1.0f / (1.0f + __expf(-ad4[b]));
        float sc  = dot - 0.5f * cb4v[b] + 0.4f * sg + acc[NH + t][r] * inv;
        int   e   = e0 + b;
        if (sc > best || (sc == best && e < bidx)) {
          best = sc; bidx = e; bdot = dot;
        }
      }
    }
  {
    float ob = __shfl_xor(best, 32);
    int   oi = __shfl_xor(bidx, 32);
    float od = __shfl_xor(bdot, 32);
    if (ob > best || (ob == best && oi < bidx)) { best = ob; bidx = oi; bdot = od; }
  }
  const float znf = zn + __shfl_xor(zn, 32);

  float lj = 0.0f;
  if (lane < 32) {
    idxf_out[gt] = (float)bidx;
    idxi_ws[gt]  = bidx;
    mark_ws[pv * K + bidx] = 1;
    lj = cbn[bidx] + znf - 2.0f * bdot;
  }
#pragma unroll
  for (int off = 32; off; off >>= 1) lj += __shfl_xor(lj, off);
  if (lane == 0) wred[wv] = lj;

  // ---- zq gather-write: wave writes its 32 token rows (1 KB each) ----
  const float4* cb4p = (const float4*)cb;
  float4* zq4 = (float4*)zq_out;
#pragma unroll 4
  for (int i = 0; i < 32; ++i) {
    int bi_i = __shfl(bidx, i);
    zq4[(size_t)(t0 + i) * 64 + lane] = cb4p[(size_t)bi_i * 64 + lane];
  }
  __syncthreads();
  if (tid == 0) lossp[blockIdx.x] = wred[0] + wred[1] + wred[2] + wred[3];
}

// ---- pass B: embed sums via one-hot MFMA (emb = P^T @ zf), counts via LDS ----
// grid = 256 chunks x 4 col-groups (64 cols each).  TPB=1024 tokens per block.
template <int K>
__global__ __launch_bounds__(256) void k_passB(
    const float* __restrict__ zre, const float* __restrict__ zim,
    const int* __restrict__ idxi,
    float* __restrict__ emb_ws, int* __restrict__ cnt_ws) {
  constexpr int TPB  = 1024;
  constexpr int NCT2 = (K == 64) ? 1 : 2;   // col-tiles per wave
  __shared__ int idxl[TPB];
  __shared__ int cntl[K];
  const int tid  = threadIdx.x;
  const int lane = tid & 63, wv = tid >> 6;
  const int chunk = blockIdx.x >> 2;        // 0..255
  const int cg    = blockIdx.x & 3;         // which 64 of the 256 cols
  const int tbase = chunk * TPB;

  if (tid < K) cntl[tid] = 0;
  __syncthreads();
#pragma unroll
  for (int i = 0; i < TPB / 256; ++i) {
    int id = idxi[tbase + i * 256 + tid];
    idxl[i * 256 + tid] = id;
    if (cg == 0) atomicAdd(&cntl[id], 1);
  }
  __syncthreads();
  if (cg == 0 && tid < K) atomicAdd(&cnt_ws[tid], cntl[tid]);

  const int rt  = (K == 64) ? (wv & 1) : wv;
  const int ct0 = (K == 64) ? (wv >> 1) : 0;
  const int krow = rt * 32 + (lane & 31);
  const int esub = (lane >> 5) * 8;
  const float* zsrc = (cg < 2) ? zre : zim;
  const int cbase = (cg & 1) * 64;          // col base within this z tensor

  f32x16 acc[NCT2];
#pragma unroll
  for (int c = 0; c < NCT2; ++c)
#pragma unroll
    for (int r = 0; r < 16; ++r) acc[c][r] = 0.0f;

  const _Float16 oneh = (_Float16)1.0f, zeroh = (_Float16)0.0f;
  for (int s = 0; s < TPB / 16; ++s) {
    const int tloc = s * 16 + esub;
    f16x8 Af;
#pragma unroll
    for (int e = 0; e < 8; ++e)
      Af[e] = (idxl[tloc + e] == krow) ? oneh : zeroh;
#pragma unroll
    for (int c = 0; c < NCT2; ++c) {
      const float* zp = zsrc + (size_t)(tbase + tloc) * LATD
                        + cbase + (ct0 + c) * 32 + (lane & 31);
      f16x8 Bf;
#pragma unroll
      for (int e = 0; e < 8; ++e)
        Bf[e] = (_Float16)zp[(size_t)e * LATD];
      acc[c] = __builtin_amdgcn_mfma_f32_32x32x16_f16(Af, Bf, acc[c], 0, 0, 0);
    }
  }
#pragma unroll
  for (int c = 0; c < NCT2; ++c)
#pragma unroll
    for (int r = 0; r < 16; ++r) {
      int row = rt * 32 + (r & 3) + 8 * (r >> 2) + 4 * (lane >> 5);
      int col = cg * 64 + (ct0 + c) * 32 + (lane & 31);
      atomicAdd(&emb_ws[row * DIMD + col], acc[c][r]);
    }
}

// ---- finalize 1: cl_new, n sums, loss ----
__global__ __launch_bounds__(256) void k_fin1(
    float* __restrict__ ws, const float* __restrict__ clsi, const float* __restrict__ clmi,
    float* __restrict__ out_cl_syn, float* __restrict__ out_cl_sem, float* __restrict__ out_loss) {
  __shared__ float red[256];
  __shared__ float s1[64], s2[128];
  const int* wsi = (const int*)ws;
  int tid = threadIdx.x;
  float s = 0.0f;
  for (int i = tid; i < 2048; i += 256) s += ws[W_LOSSP_SYN + i];
  for (int i = tid; i < 2048; i += 256) s += ws[W_LOSSP_SEM + i];
  red[tid] = s;
  if (tid < 64) {
    float c  = (float)wsi[W_CNT_SYN + tid];
    float cl = clsi[tid] * 0.99f + 0.01f * c;
    out_cl_syn[tid] = cl; s1[tid] = cl;
  }
  if (tid < 128) {
    float c  = (float)wsi[W_CNT_SEM + tid];
    float cl = clmi[tid] * 0.99f + 0.01f * c;
    out_cl_sem[tid] = cl; s2[tid] = cl;
  }
  __syncthreads();
  for (int st = 128; st > 0; st >>= 1) {
    if (tid < st) red[tid] += red[tid + st];
    __syncthreads();
  }
  if (tid == 0) {
    float n1 = 0.0f; for (int i = 0; i < 64;  ++i) n1 += s1[i];
    float n2 = 0.0f; for (int i = 0; i < 128; ++i) n2 += s2[i];
    ws[W_LOSSP_SYN + 4096] = n1;   // stash n_syn
    ws[W_LOSSP_SEM + 4096] = n2;   // stash n_sem
    float denom = (float)N_TOK * 256.0f;
    *out_loss = 1.25f * red[0] / denom;
  }
}

// ---- finalize 2: avg_new, cb_new, adj_new ----
__global__ __launch_bounds__(256) void k_fin2(
    const float* __restrict__ ws,
    const float* __restrict__ avgs, const float* __restrict__ avgm,
    const float* __restrict__ adjs, const float* __restrict__ adjm,
    const float* __restrict__ clsi, const float* __restrict__ clmi,
    float* __restrict__ o_cb_syn, float* __restrict__ o_avg_syn, float* __restrict__ o_adj_syn,
    float* __restrict__ o_cb_sem, float* __restrict__ o_avg_sem, float* __restrict__ o_adj_sem) {
  const int* wsi = (const int*)ws;
  int e = blockIdx.x * 256 + threadIdx.x;
  if (e < 16384) {                       // syn avg/cb
    int k = e >> 8;
    float av = avgs[e] * 0.99f + 0.01f * ws[W_EMB_SYN + e];
    o_avg_syn[e] = av;
    float cnt = (float)wsi[W_CNT_SYN + k];
    float cl  = clsi[k] * 0.99f + 0.01f * cnt;
    float n   = ws[W_LOSSP_SYN + 4096];
    float cs  = (cl + 1e-6f) / (n + (float)(64 * 1e-6)) * n;
    o_cb_syn[e] = av / cs;
  } else if (e < 49152) {                // sem avg/cb
    int e2 = e - 16384;
    int k = e2 >> 8;
    float av = avgm[e2] * 0.99f + 0.01f * ws[W_EMB_SEM + e2];
    o_avg_sem[e2] = av;
    float cnt = (float)wsi[W_CNT_SEM + k];
    float cl  = clmi[k] * 0.99f + 0.01f * cnt;
    float n   = ws[W_LOSSP_SEM + 4096];
    float cs  = (cl + 1e-6f) / (n + (float)(128 * 1e-6)) * n;
    o_cb_sem[e2] = av / cs;
  } else if (e < 53248) {                // adj syn
    int a = e - 49152;
    float old = adjs[a];
    o_adj_syn[a] = wsi[W_MRK_SYN + a] ? old * 0.995f + 1.0f : old;
  } else if (e < 69632) {                // adj sem
    int a = e - 53248;
    float old = adjm[a];
    o_adj_sem[a] = wsi[W_MRK_SEM + a] ? old * 0.995f + 1.0f : old;
  }
}

extern "C" void kernel_launch(void* const* d_in, const int* in_sizes, int n_in,
                              void* d_out, int out_size, void* d_ws, size_t ws_size,
                              hipStream_t stream) {
  const float* zfre = (const float*)d_in[0];
  const float* zfim = (const float*)d_in[1];
  const float* zsre = (const float*)d_in[2];
  const float* zsim = (const float*)d_in[3];
  const float* cbs  = (const float*)d_in[4];
  const float* cbm  = (const float*)d_in[5];
  const float* Wsy  = (const float*)d_in[6];
  const float* bsy  = (const float*)d_in[7];
  const float* Wse  = (const float*)d_in[8];
  const float* bse  = (const float*)d_in[9];
  const float* clsi = (const float*)d_in[10];
  const float* avgs = (const float*)d_in[11];
  const float* clmi = (const float*)d_in[12];
  const float* avgm = (const float*)d_in[13];
  const float* adjs = (const float*)d_in[14];
  const float* adjm = (const float*)d_in[15];
  const int*   prvs = (const int*)d_in[16];
  const int*   prvm = (const int*)d_in[17];

  float* out = (float*)d_out;
  float* wsf = (float*)d_ws;
  int*   wsi = (int*)d_ws;
  _Float16* wsh = (_Float16*)d_ws;

  k_init<<<(W_ZERO_END - W_ZERO_BEG + 255) / 256, 256, 0, stream>>>(wsf);
  k_prep_pack<64><<<128, 256, 0, stream>>>(cbs, Wsy, wsh + 2 * W_PACK_SYN);
  k_prep_pack<128><<<256, 256, 0, stream>>>(cbm, Wse, wsh + 2 * W_PACK_SEM);
  k_prep_norm<<<192, 256, 0, stream>>>(cbs, cbm, wsf);

  k_passA<64><<<N_TOK / 128, 256, 0, stream>>>(
      zfre, zfim, wsh + 2 * W_PACK_SYN, wsf + W_CBN_SYN, cbs, bsy, adjs, prvs,
      out + OFF_ZQ_SYN, out + OFF_IDX_SYN, wsi + W_IDX_SYN, wsi + W_MRK_SYN,
      wsf + W_LOSSP_SYN);
  k_passA<128><<<N_TOK / 128, 256, 0, stream>>>(
      zsre, zsim, wsh + 2 * W_PACK_SEM, wsf + W_CBN_SEM, cbm, bse, adjm, prvm,
      out + OFF_ZQ_SEM, out + OFF_IDX_SEM, wsi + W_IDX_SEM, wsi + W_MRK_SEM,
      wsf + W_LOSSP_SEM);

  k_passB<64><<<1024, 256, 0, stream>>>(
      zfre, zfim, wsi + W_IDX_SYN, wsf + W_EMB_SYN, wsi + W_CNT_SYN);
  k_passB<128><<<1024, 256, 0, stream>>>(
      zsre, zsim, wsi + W_IDX_SEM, wsf + W_EMB_SEM, wsi + W_CNT_SEM);

  k_fin1<<<1, 256, 0, stream>>>(wsf, clsi, clmi,
      out + OFF_CL_SYN, out + OFF_CL_SEM, out + OFF_LOSS);
  k_fin2<<<272, 256, 0, stream>>>(wsf, avgs, avgm, adjs, adjm, clsi, clmi,
      out + OFF_CB_SYN, out + OFF_AVG_SYN, out + OFF_ADJ_SYN,
      out + OFF_CB_SEM, out + OFF_AVG_SEM, out + OFF_ADJ_SEM);
}

// Round 8
// 567.398 us; speedup vs baseline: 1.5739x; 1.1694x over previous
//
#include <hip/hip_runtime.h>

#define N_TOK 262144
#define LATD  128
#define DIMD  256

using f32x4  = __attribute__((ext_vector_type(4)))  float;
using f32x16 = __attribute__((ext_vector_type(16))) float;
using f16x8  = __attribute__((ext_vector_type(8)))  _Float16;
using f16x2  = __attribute__((ext_vector_type(2)))  _Float16;

// ---------------- workspace layout (32-bit word offsets) ----------------
#define W_PACK_SYN 0         // 65536 f16 (32768 words): [kt][hi/lo][ct][lane][e]
#define W_PACK_SEM 32768     // 131072 f16 (65536 words)
#define W_CBN_SYN  98304     // 64  f32 ||cb||^2
#define W_CBN_SEM  98368     // 128 f32
#define W_IDX_SYN  98496     // 262144 i32
#define W_IDX_SEM  360640    // 262144 i32
#define W_CNT_SYN  622784    // 64  i32
#define W_CNT_SEM  622848    // 128 i32
#define W_EMB_SYN  622976    // 64x256 f32
#define W_EMB_SEM  639360    // 128x256 f32
#define W_MRK_SYN  672128    // 64x64 i32
#define W_MRK_SEM  676224    // 128x128 i32
#define W_LOSSP_SYN 692612   // 2048 f32 per-block loss partials (+n stash at +4096)
#define W_LOSSP_SEM 700804   // 2048 f32 (+n stash at +4096)
#define W_ZERO_BEG 622784
#define W_ZERO_END 692612

// ---------------- output layout (float offsets) ----------------
#define OFF_ZQ_SYN  0LL
#define OFF_ZQ_SEM  67108864LL
#define OFF_LOSS    134217728LL
#define OFF_IDX_SYN 134217729LL
#define OFF_IDX_SEM 134479873LL
#define OFF_CB_SYN  134742017LL
#define OFF_CL_SYN  134758401LL
#define OFF_AVG_SYN 134758465LL
#define OFF_ADJ_SYN 134774849LL
#define OFF_CB_SEM  134778945LL
#define OFF_CL_SEM  134811713LL
#define OFF_AVG_SEM 134811841LL
#define OFF_ADJ_SEM 134844609LL

__global__ __launch_bounds__(256) void k_init(float* __restrict__ ws) {
  int idx = W_ZERO_BEG + blockIdx.x * 256 + threadIdx.x;
  if (idx < W_ZERO_END) ws[idx] = 0.0f;
}

// Pack Mt = [cb^T | W] into 32x32x16 f16 fragment order, hi + lo halves.
template <int K>
__global__ __launch_bounds__(256) void k_prep_pack(
    const float* __restrict__ cb, const float* __restrict__ W,
    _Float16* __restrict__ pack) {
  constexpr int R   = 2 * K;
  constexpr int NCT = R / 32;
  constexpr int PER_KT = NCT * 512;
  int t = blockIdx.x * 256 + threadIdx.x;   // < 16*PER_KT
  int kt = t / PER_KT;
  int r  = t - kt * PER_KT;
  int ct = r >> 9;
  int l  = (r >> 3) & 63;
  int e  = r & 7;
  int j   = kt * 16 + (l >> 5) * 8 + e;
  int col = ct * 32 + (l & 31);
  float x = (col < K) ? cb[col * DIMD + j] : W[j * K + (col - K)];
  _Float16 h = (_Float16)x;
  _Float16 lo = (_Float16)(x - (float)h);
  pack[(size_t)kt * 2 * PER_KT + r]          = h;
  pack[(size_t)kt * 2 * PER_KT + PER_KT + r] = lo;
}

// ||cb_k||^2.  grid = 192 blocks (64 syn + 128 sem), 256 threads.
__global__ __launch_bounds__(256) void k_prep_norm(
    const float* __restrict__ cbs, const float* __restrict__ cbm,
    float* __restrict__ ws) {
  __shared__ float red[256];
  int k = blockIdx.x;
  const float* src;
  float* dst;
  if (k < 64) { src = cbs + (size_t)k * DIMD; dst = ws + W_CBN_SYN + k; }
  else        { src = cbm + (size_t)(k - 64) * DIMD; dst = ws + W_CBN_SEM + (k - 64); }
  float v = src[threadIdx.x];
  red[threadIdx.x] = v * v;
  __syncthreads();
  for (int s = 128; s > 0; s >>= 1) {
    if (threadIdx.x < s) red[threadIdx.x] += red[threadIdx.x + s];
    __syncthreads();
  }
  if (threadIdx.x == 0) *dst = red[0];
}

// ---- pass A: merged-role, LDS-free swapped-operand split-f16 MFMA ----
// Each wave owns 32 tokens, computes ALL 2K entry rows.  z prefetched one
// K-chunk ahead to hide HBM latency.  Epilogue fully register-local.
template <int K>
__global__ __launch_bounds__(256, 2) void k_passA(
    const float* __restrict__ zre, const float* __restrict__ zim,
    const _Float16* __restrict__ pack, const float* __restrict__ cbn,
    const float* __restrict__ cb,  const float* __restrict__ bvec,
    const float* __restrict__ adj, const int* __restrict__ prev,
    float* __restrict__ zq_out, float* __restrict__ idxf_out,
    int* __restrict__ idxi_ws, int* __restrict__ mark_ws,
    float* __restrict__ lossp) {
  constexpr int NCT = K / 16;           // total 32-row tiles: 4 / 8
  constexpr int NH  = K / 32;           // tiles per role: 2 / 4
  constexpr int PER_KT = NCT * 512;     // f16 per hi (or lo) k-chunk
  __shared__ float wred[4];

  const int tid  = threadIdx.x;
  const int lane = tid & 63;
  const int wv   = tid >> 6;
  const int kg   = lane >> 5;
  const int j    = lane & 31;
  const int t0   = blockIdx.x * 128 + wv * 32;
  const int gt   = t0 + j;              // this lane's token

  f32x16 acc[NCT];
#pragma unroll
  for (int t = 0; t < NCT; ++t)
#pragma unroll
    for (int r = 0; r < 16; ++r) acc[t][r] = 0.0f;
  float zn = 0.0f;

  f32x4 v0, v1, nv0, nv1;
  {
    const float* zp = zre + (size_t)gt * LATD + kg * 8;
    v0 = *(const f32x4*)zp;
    v1 = *(const f32x4*)(zp + 4);
  }
#pragma unroll 2
  for (int kt = 0; kt < 16; ++kt) {
    if (kt + 1 < 16) {                  // prefetch next chunk's z early
      const float* zsrc2 = (kt + 1 < 8) ? zre : zim;
      const float* zp2 = zsrc2 + (size_t)gt * LATD + ((kt + 1) & 7) * 16 + kg * 8;
      nv0 = *(const f32x4*)zp2;
      nv1 = *(const f32x4*)(zp2 + 4);
    }
    f16x8 Bh, Bl;
#pragma unroll
    for (int e = 0; e < 4; ++e) {
      _Float16 h0 = (_Float16)v0[e];
      Bh[e] = h0;       Bl[e] = (_Float16)(v0[e] - (float)h0);
      _Float16 h1 = (_Float16)v1[e];
      Bh[e + 4] = h1;   Bl[e + 4] = (_Float16)(v1[e] - (float)h1);
      zn += v0[e] * v0[e];
      zn += v1[e] * v1[e];
    }
    const _Float16* pk = pack + (size_t)kt * 2 * PER_KT + lane * 8;
#pragma unroll
    for (int t = 0; t < NCT; ++t) {
      f16x8 Ah = *(const f16x8*)(pk + (size_t)t * 512);
      f16x8 Al = *(const f16x8*)(pk + PER_KT + (size_t)t * 512);
      acc[t] = __builtin_amdgcn_mfma_f32_32x32x16_f16(Ah, Bh, acc[t], 0, 0, 0);
      acc[t] = __builtin_amdgcn_mfma_f32_32x32x16_f16(Ah, Bl, acc[t], 0, 0, 0);
      acc[t] = __builtin_amdgcn_mfma_f32_32x32x16_f16(Al, Bh, acc[t], 0, 0, 0);
    }
    v0 = nv0; v1 = nv1;
  }

  const int pv = prev[gt];

  // ---- softmax over logit tiles (NH..NCT-1), in-register ----
  float mx = -1e30f;
#pragma unroll
  for (int t = 0; t < NH; ++t)
#pragma unroll
    for (int q = 0; q < 4; ++q) {
      f32x4 bv4 = *(const f32x4*)&bvec[t * 32 + 8 * q + 4 * kg];
#pragma unroll
      for (int b = 0; b < 4; ++b) {
        acc[NH + t][4 * q + b] += bv4[b];
        mx = fmaxf(mx, acc[NH + t][4 * q + b]);
      }
    }
  mx = fmaxf(mx, __shfl_xor(mx, 32));
  float es = 0.0f;
#pragma unroll
  for (int t = 0; t < NH; ++t)
#pragma unroll
    for (int r = 0; r < 16; ++r) {
      acc[NH + t][r] = __expf(acc[NH + t][r] - mx);
      es += acc[NH + t][r];
    }
  es += __shfl_xor(es, 32);
  const float inv = 1.0f / es;

  // ---- biased argmin (as argmax of sc = dot - cbn/2 + 0.4 sg + p) ----
  const float* adjrow = adj + (size_t)pv * K;
  float best = -1e30f; int bidx = 0; float bdot = 0.0f;
#pragma unroll
  for (int t = 0; t < NH; ++t)
#pragma unroll
    for (int q = 0; q < 4; ++q) {
      const int e0 = t * 32 + 8 * q + 4 * kg;
      f32x4 cb4v = *(const f32x4*)&cbn[e0];
      f32x4 ad4  = *(const f32x4*)&adjrow[e0];
#pragma unroll
      for (int b = 0; b < 4; ++b) {
        int r = 4 * q + b;
        float dot = acc[t][r];
        float sg  = 1.0f / (1.0f + __expf(-ad4[b]));
        float sc  = dot - 0.5f * cb4v[b] + 0.4f * sg + acc[NH + t][r] * inv;
        int   e   = e0 + b;
        if (sc > best || (sc == best && e < bidx)) {
          best = sc; bidx = e; bdot = dot;
        }
      }
    }
  {
    float ob = __shfl_xor(best, 32);
    int   oi = __shfl_xor(bidx, 32);
    float od = __shfl_xor(bdot, 32);
    if (ob > best || (ob == best && oi < bidx)) { best = ob; bidx = oi; bdot = od; }
  }
  const float znf = zn + __shfl_xor(zn, 32);

  float lj = 0.0f;
  if (lane < 32) {
    idxf_out[gt] = (float)bidx;
    idxi_ws[gt]  = bidx;
    mark_ws[pv * K + bidx] = 1;
    lj = cbn[bidx] + znf - 2.0f * bdot;
  }
#pragma unroll
  for (int off = 32; off; off >>= 1) lj += __shfl_xor(lj, off);
  if (lane == 0) wred[wv] = lj;

  // ---- zq gather-write: wave writes its 32 token rows (1 KB each) ----
  const float4* cb4p = (const float4*)cb;
  float4* zq4 = (float4*)zq_out;
#pragma unroll 4
  for (int i = 0; i < 32; ++i) {
    int bi_i = __shfl(bidx, i);
    zq4[(size_t)(t0 + i) * 64 + lane] = cb4p[(size_t)bi_i * 64 + lane];
  }
  __syncthreads();
  if (tid == 0) lossp[blockIdx.x] = wred[0] + wred[1] + wred[2] + wred[3];
}

// ---- pass B: embed sums via one-hot MFMA (emb = P^T @ zf) ----
// grid = 256 chunks x 4 col-groups.  TPB=1024 tokens per block.
// z staged per 128-token sub-chunk into LDS as f16 TRANSPOSED [col][token]
// (XOR-swizzled), so each B-fragment is ONE ds_read_b128.
template <int K>
__global__ __launch_bounds__(256) void k_passB(
    const float* __restrict__ zre, const float* __restrict__ zim,
    const int* __restrict__ idxi,
    float* __restrict__ emb_ws, int* __restrict__ cnt_ws) {
  constexpr int TPB  = 1024;
  constexpr int CH   = 128;                 // tokens per LDS sub-chunk
  constexpr int NCT2 = (K == 64) ? 1 : 2;   // col-tiles per wave
  __shared__ int idxl[TPB];
  __shared__ int cntl[K];
  __shared__ __align__(16) unsigned short zT[64 * CH];  // [col][token] f16, swizzled
  const int tid  = threadIdx.x;
  const int lane = tid & 63, wv = tid >> 6;
  const int chunk = blockIdx.x >> 2;        // 0..255
  const int cg    = blockIdx.x & 3;         // which 64 of the 256 cols
  const int tbase = chunk * TPB;

  if (tid < K) cntl[tid] = 0;
  __syncthreads();
#pragma unroll
  for (int i = 0; i < TPB / 256; ++i) {
    int id = idxi[tbase + i * 256 + tid];
    idxl[i * 256 + tid] = id;
    if (cg == 0) atomicAdd(&cntl[id], 1);
  }
  __syncthreads();
  if (cg == 0 && tid < K) atomicAdd(&cnt_ws[tid], cntl[tid]);

  const int rt  = (K == 64) ? (wv & 1) : wv;
  const int ct0 = (K == 64) ? (wv >> 1) : 0;
  const int krow = rt * 32 + (lane & 31);
  const int kg   = lane >> 5;
  const float* zsrc = (cg < 2) ? zre : zim;
  const int cbase = (cg & 1) * 64;          // col base within this z tensor

  f32x16 acc[NCT2];
#pragma unroll
  for (int c = 0; c < NCT2; ++c)
#pragma unroll
    for (int r = 0; r < 16; ++r) acc[c][r] = 0.0f;

  const int sq = tid & 15;                  // staging col-quad
  const int sp = tid >> 4;                  // staging pair base (0..15)

  for (int sc = 0; sc < TPB / CH; ++sc) {
    // ---- stage sub-chunk: transpose to [col][token] f16 with swizzle ----
#pragma unroll
    for (int it = 0; it < 4; ++it) {
      int p = sp + it * 16;                 // token pair 0..63
      int t = sc * CH + 2 * p;
      const float* zr = zsrc + (size_t)(tbase + t) * LATD + cbase + 4 * sq;
      f32x4 a = *(const f32x4*)zr;
      f32x4 b = *(const f32x4*)(zr + LATD);
#pragma unroll
      for (int c4 = 0; c4 < 4; ++c4) {
        int c = 4 * sq + c4;
        f16x2 pr;
        pr[0] = (_Float16)a[c4];
        pr[1] = (_Float16)b[c4];
        int byte = c * 256 + ((4 * p) ^ ((c & 7) << 4));
        *(f16x2*)((char*)zT + byte) = pr;
      }
    }
    __syncthreads();
    // ---- MFMA over 8 steps of 16 tokens ----
#pragma unroll
    for (int st = 0; st < 8; ++st) {
      const int tloc = sc * CH + st * 16 + kg * 8;
      f16x8 Af;
#pragma unroll
      for (int e = 0; e < 8; ++e)
        Af[e] = (idxl[tloc + e] == krow) ? (_Float16)1.0f : (_Float16)0.0f;
#pragma unroll
      for (int c = 0; c < NCT2; ++c) {
        int col = (ct0 + c) * 32 + (lane & 31);
        int byte = col * 256 + (((st * 32 + kg * 16)) ^ ((col & 7) << 4));
        f16x8 Bf = *(const f16x8*)((const char*)zT + byte);
        acc[c] = __builtin_amdgcn_mfma_f32_32x32x16_f16(Af, Bf, acc[c], 0, 0, 0);
      }
    }
    __syncthreads();
  }
#pragma unroll
  for (int c = 0; c < NCT2; ++c)
#pragma unroll
    for (int r = 0; r < 16; ++r) {
      int row = rt * 32 + (r & 3) + 8 * (r >> 2) + 4 * (lane >> 5);
      int col = cg * 64 + (ct0 + c) * 32 + (lane & 31);
      atomicAdd(&emb_ws[row * DIMD + col], acc[c][r]);
    }
}

// ---- finalize 1: cl_new, n sums, loss ----
__global__ __launch_bounds__(256) void k_fin1(
    float* __restrict__ ws, const float* __restrict__ clsi, const float* __restrict__ clmi,
    float* __restrict__ out_cl_syn, float* __restrict__ out_cl_sem, float* __restrict__ out_loss) {
  __shared__ float red[256];
  __shared__ float s1[64], s2[128];
  const int* wsi = (const int*)ws;
  int tid = threadIdx.x;
  float s = 0.0f;
  for (int i = tid; i < 2048; i += 256) s += ws[W_LOSSP_SYN + i];
  for (int i = tid; i < 2048; i += 256) s += ws[W_LOSSP_SEM + i];
  red[tid] = s;
  if (tid < 64) {
    float c  = (float)wsi[W_CNT_SYN + tid];
    float cl = clsi[tid] * 0.99f + 0.01f * c;
    out_cl_syn[tid] = cl; s1[tid] = cl;
  }
  if (tid < 128) {
    float c  = (float)wsi[W_CNT_SEM + tid];
    float cl = clmi[tid] * 0.99f + 0.01f * c;
    out_cl_sem[tid] = cl; s2[tid] = cl;
  }
  __syncthreads();
  for (int st = 128; st > 0; st >>= 1) {
    if (tid < st) red[tid] += red[tid + st];
    __syncthreads();
  }
  if (tid == 0) {
    float n1 = 0.0f; for (int i = 0; i < 64;  ++i) n1 += s1[i];
    float n2 = 0.0f; for (int i = 0; i < 128; ++i) n2 += s2[i];
    ws[W_LOSSP_SYN + 4096] = n1;   // stash n_syn
    ws[W_LOSSP_SEM + 4096] = n2;   // stash n_sem
    float denom = (float)N_TOK * 256.0f;
    *out_loss = 1.25f * red[0] / denom;
  }
}

// ---- finalize 2: avg_new, cb_new, adj_new ----
__global__ __launch_bounds__(256) void k_fin2(
    const float* __restrict__ ws,
    const float* __restrict__ avgs, const float* __restrict__ avgm,
    const float* __restrict__ adjs, const float* __restrict__ adjm,
    const float* __restrict__ clsi, const float* __restrict__ clmi,
    float* __restrict__ o_cb_syn, float* __restrict__ o_avg_syn, float* __restrict__ o_adj_syn,
    float* __restrict__ o_cb_sem, float* __restrict__ o_avg_sem, float* __restrict__ o_adj_sem) {
  const int* wsi = (const int*)ws;
  int e = blockIdx.x * 256 + threadIdx.x;
  if (e < 16384) {                       // syn avg/cb
    int k = e >> 8;
    float av = avgs[e] * 0.99f + 0.01f * ws[W_EMB_SYN + e];
    o_avg_syn[e] = av;
    float cnt = (float)wsi[W_CNT_SYN + k];
    float cl  = clsi[k] * 0.99f + 0.01f * cnt;
    float n   = ws[W_LOSSP_SYN + 4096];
    float cs  = (cl + 1e-6f) / (n + (float)(64 * 1e-6)) * n;
    o_cb_syn[e] = av / cs;
  } else if (e < 49152) {                // sem avg/cb
    int e2 = e - 16384;
    int k = e2 >> 8;
    float av = avgm[e2] * 0.99f + 0.01f * ws[W_EMB_SEM + e2];
    o_avg_sem[e2] = av;
    float cnt = (float)wsi[W_CNT_SEM + k];
    float cl  = clmi[k] * 0.99f + 0.01f * cnt;
    float n   = ws[W_LOSSP_SEM + 4096];
    float cs  = (cl + 1e-6f) / (n + (float)(128 * 1e-6)) * n;
    o_cb_sem[e2] = av / cs;
  } else if (e < 53248) {                // adj syn
    int a = e - 49152;
    float old = adjs[a];
    o_adj_syn[a] = wsi[W_MRK_SYN + a] ? old * 0.995f + 1.0f : old;
  } else if (e < 69632) {                // adj sem
    int a = e - 53248;
    float old = adjm[a];
    o_adj_sem[a] = wsi[W_MRK_SEM + a] ? old * 0.995f + 1.0f : old;
  }
}

extern "C" void kernel_launch(void* const* d_in, const int* in_sizes, int n_in,
                              void* d_out, int out_size, void* d_ws, size_t ws_size,
                              hipStream_t stream) {
  const float* zfre = (const float*)d_in[0];
  const float* zfim = (const float*)d_in[1];
  const float* zsre = (const float*)d_in[2];
  const float* zsim = (const float*)d_in[3];
  const float* cbs  = (const float*)d_in[4];
  const float* cbm  = (const float*)d_in[5];
  const float* Wsy  = (const float*)d_in[6];
  const float* bsy  = (const float*)d_in[7];
  const float* Wse  = (const float*)d_in[8];
  const float* bse  = (const float*)d_in[9];
  const float* clsi = (const float*)d_in[10];
  const float* avgs = (const float*)d_in[11];
  const float* clmi = (const float*)d_in[12];
  const float* avgm = (const float*)d_in[13];
  const float* adjs = (const float*)d_in[14];
  const float* adjm = (const float*)d_in[15];
  const int*   prvs = (const int*)d_in[16];
  const int*   prvm = (const int*)d_in[17];

  float* out = (float*)d_out;
  float* wsf = (float*)d_ws;
  int*   wsi = (int*)d_ws;
  _Float16* wsh = (_Float16*)d_ws;

  k_init<<<(W_ZERO_END - W_ZERO_BEG + 255) / 256, 256, 0, stream>>>(wsf);
  k_prep_pack<64><<<128, 256, 0, stream>>>(cbs, Wsy, wsh + 2 * W_PACK_SYN);
  k_prep_pack<128><<<256, 256, 0, stream>>>(cbm, Wse, wsh + 2 * W_PACK_SEM);
  k_prep_norm<<<192, 256, 0, stream>>>(cbs, cbm, wsf);

  k_passA<64><<<N_TOK / 128, 256, 0, stream>>>(
      zfre, zfim, wsh + 2 * W_PACK_SYN, wsf + W_CBN_SYN, cbs, bsy, adjs, prvs,
      out + OFF_ZQ_SYN, out + OFF_IDX_SYN, wsi + W_IDX_SYN, wsi + W_MRK_SYN,
      wsf + W_LOSSP_SYN);
  k_passA<128><<<N_TOK / 128, 256, 0, stream>>>(
      zsre, zsim, wsh + 2 * W_PACK_SEM, wsf + W_CBN_SEM, cbm, bse, adjm, prvm,
      out + OFF_ZQ_SEM, out + OFF_IDX_SEM, wsi + W_IDX_SEM, wsi + W_MRK_SEM,
      wsf + W_LOSSP_SEM);

  k_passB<64><<<1024, 256, 0, stream>>>(
      zfre, zfim, wsi + W_IDX_SYN, wsf + W_EMB_SYN, wsi + W_CNT_SYN);
  k_passB<128><<<1024, 256, 0, stream>>>(
      zsre, zsim, wsi + W_IDX_SEM, wsf + W_EMB_SEM, wsi + W_CNT_SEM);

  k_fin1<<<1, 256, 0, stream>>>(wsf, clsi, clmi,
      out + OFF_CL_SYN, out + OFF_CL_SEM, out + OFF_LOSS);
  k_fin2<<<272, 256, 0, stream>>>(wsf, avgs, avgm, adjs, adjm, clsi, clmi,
      out + OFF_CB_SYN, out + OFF_AVG_SYN, out + OFF_ADJ_SYN,
      out + OFF_CB_SEM, out + OFF_AVG_SEM, out + OFF_ADJ_SEM);
}